// Round 2
// baseline (191.451 us; speedup 1.0000x reference)
//
#include <hip/hip_runtime.h>

// ONINorm: g=16 groups, n=128 rows/group, d=9216 cols, T=5 Newton-Schulz iters.
// Pipeline: center -> S=Zc*Zc^T -> normalize -> NS iterations -> W=B*Zc/sqrt(norm).

#define G 16
#define NROW 128
#define D 9216
#define OC 2048
#define KSPLIT 18
#define KCHUNK 512   // D / KSPLIT
#define EPSV 1e-5f

typedef float f32x16 __attribute__((ext_vector_type(16)));
typedef __bf16 bf16x8 __attribute__((ext_vector_type(8)));

union Frag {
    uint4 q;
    unsigned short s[8];
    bf16x8 v;
};

static __device__ __forceinline__ unsigned short f2bf(float x) {
    union { float f; unsigned int u; } a; a.f = x;
    unsigned int u = a.u;
    unsigned int r = u + 0x7FFFu + ((u >> 16) & 1u);   // RNE, inputs are finite
    return (unsigned short)(r >> 16);
}

static __device__ __forceinline__ float bf2f(unsigned short s) {
    union { unsigned int u; float f; } a; a.u = ((unsigned int)s) << 16;
    return a.f;
}

// Swizzled 128x128 bf16 matrix layout (element index). Granule = 8 elems = 16B.
// addr(r,c) = r*128 + ((c/8) ^ (r&15))*8 + c%8  -> frag reads are one ds_read_b128,
// rows r and r+16 share banks (2-way = free), others distinct.
static __device__ __forceinline__ int swz(int r, int c) {
    return (r << 7) + ((((c >> 3) ^ (r & 15)) << 3) | (c & 7));
}

// ---------------------------------------------------------------- K1: center
__global__ __launch_bounds__(256) void k_center(const float* __restrict__ W,
                                                unsigned short* __restrict__ Zc) {
    int row = blockIdx.x;
    int t = threadIdx.x;
    const float4* wp = (const float4*)(W + (size_t)row * D);
    float4 v[9];
    float s = 0.f;
#pragma unroll
    for (int i = 0; i < 9; i++) {
        v[i] = wp[t + i * 256];
        s += v[i].x + v[i].y + v[i].z + v[i].w;
    }
#pragma unroll
    for (int o = 32; o > 0; o >>= 1) s += __shfl_down(s, o, 64);
    __shared__ float ls[4];
    if ((t & 63) == 0) ls[t >> 6] = s;
    __syncthreads();
    float mean = (ls[0] + ls[1] + ls[2] + ls[3]) * (1.0f / 9216.0f);
    ushort4* zp = (ushort4*)(Zc + (size_t)row * D);
#pragma unroll
    for (int i = 0; i < 9; i++) {
        ushort4 o4;
        o4.x = f2bf(v[i].x - mean);
        o4.y = f2bf(v[i].y - mean);
        o4.z = f2bf(v[i].z - mean);
        o4.w = f2bf(v[i].w - mean);
        zp[t + i * 256] = o4;
    }
}

// ------------------------------------------------- K2: S partial GEMM (k-split)
// block (g, ks): S_part = Zc[:, chunk] * Zc[:, chunk]^T, both operands = same tile.
__global__ __launch_bounds__(256) void k_sgemm(const unsigned short* __restrict__ Zc,
                                               float* __restrict__ Spart) {
    __shared__ unsigned short tile[NROW * 128];
    int bid = blockIdx.x;
    int g = bid / KSPLIT, ks = bid % KSPLIT;
    int t = threadIdx.x, lane = t & 63, wave = t >> 6;
    int mq = (wave & 1) * 64, nq = (wave >> 1) * 64;
    int m = lane & 31, h = lane >> 5;

    f32x16 acc[2][2];
#pragma unroll
    for (int i = 0; i < 2; i++)
#pragma unroll
        for (int j = 0; j < 2; j++)
#pragma unroll
            for (int z = 0; z < 16; z++) acc[i][j][z] = 0.f;

    const unsigned short* zg = Zc + (size_t)g * NROW * D + ks * KCHUNK;

    for (int step = 0; step < 4; step++) {
        int dbase = step * 128;
        __syncthreads();
#pragma unroll
        for (int p = 0; p < 8; p++) {
            int flat = p * 256 + t;
            int r = flat >> 4, gc = flat & 15;
            uint4 dd = *(const uint4*)(zg + (size_t)r * D + dbase + gc * 8);
            *(uint4*)(tile + swz(r, gc * 8)) = dd;
        }
        __syncthreads();
#pragma unroll
        for (int kk = 0; kk < 8; kk++) {
            int kb = kk * 16 + h * 8;
            Frag a0, a1, b0, b1;
            a0.q = *(const uint4*)(tile + swz(mq + m, kb));
            a1.q = *(const uint4*)(tile + swz(mq + 32 + m, kb));
            b0.q = *(const uint4*)(tile + swz(nq + m, kb));
            b1.q = *(const uint4*)(tile + swz(nq + 32 + m, kb));
            acc[0][0] = __builtin_amdgcn_mfma_f32_32x32x16_bf16(a0.v, b0.v, acc[0][0], 0, 0, 0);
            acc[0][1] = __builtin_amdgcn_mfma_f32_32x32x16_bf16(a0.v, b1.v, acc[0][1], 0, 0, 0);
            acc[1][0] = __builtin_amdgcn_mfma_f32_32x32x16_bf16(a1.v, b0.v, acc[1][0], 0, 0, 0);
            acc[1][1] = __builtin_amdgcn_mfma_f32_32x32x16_bf16(a1.v, b1.v, acc[1][1], 0, 0, 0);
        }
    }
    float* sp = Spart + (size_t)(g * KSPLIT + ks) * 16384;
#pragma unroll
    for (int i = 0; i < 2; i++)
#pragma unroll
        for (int j = 0; j < 2; j++)
#pragma unroll
            for (int reg = 0; reg < 16; reg++) {
                int row = (reg & 3) + 8 * (reg >> 2) + 4 * h;
                sp[(mq + i * 32 + row) * 128 + nq + j * 32 + m] = acc[i][j][reg];
            }
}

// -------------------------------------- K3: reduce partials + eps*I + fro-norm acc
__global__ __launch_bounds__(256) void k_reduce(const float* __restrict__ Spart,
                                                float* __restrict__ Sred,
                                                float* __restrict__ normAcc) {
    int b = blockIdx.x;
    int g = b >> 4, part = b & 15;
    int el = part * 1024 + threadIdx.x * 4;
    float4 s = {0.f, 0.f, 0.f, 0.f};
    for (int ks = 0; ks < KSPLIT; ks++) {
        float4 p = *(const float4*)(Spart + (size_t)(g * KSPLIT + ks) * 16384 + el);
        s.x += p.x; s.y += p.y; s.z += p.z; s.w += p.w;
    }
    int r = el >> 7, c = el & 127;
    if (r >= c && r <= c + 3) {
        if (r == c) s.x += EPSV;
        else if (r == c + 1) s.y += EPSV;
        else if (r == c + 2) s.z += EPSV;
        else s.w += EPSV;
    }
    *(float4*)(Sred + (size_t)g * 16384 + el) = s;
    float sq = s.x * s.x + s.y * s.y + s.z * s.z + s.w * s.w;
#pragma unroll
    for (int o = 32; o > 0; o >>= 1) sq += __shfl_down(sq, o, 64);
    __shared__ float ls[4];
    if ((threadIdx.x & 63) == 0) ls[threadIdx.x >> 6] = sq;
    __syncthreads();
    if (threadIdx.x == 0) atomicAdd(normAcc + g, ls[0] + ls[1] + ls[2] + ls[3]);
}

// ------------------------------------------------ K4: Newton-Schulz (one blk/group)
// B1 = 1.5I - 0.5*Sn computed analytically (skips iteration 1), then 4 iterations:
//   phase1: U = B*B (bitwise symmetric -> stored transposed = itself),
//           V = B*Sn, stored transposed for use as MFMA B-operand.
//   phase2: B = 1.5*B - 0.5*U*V.
__global__ __launch_bounds__(512) void k_ns(const float* __restrict__ Sred,
                                            const float* __restrict__ normAcc,
                                            unsigned short* __restrict__ Bt) {
    extern __shared__ unsigned short sm[];
    unsigned short* Bb = sm;
    unsigned short* Sb = sm + 16384;
    unsigned short* Ub = sm + 32768;
    unsigned short* Vt = sm + 49152;
    int g = blockIdx.x;
    int t = threadIdx.x, lane = t & 63, wave = t >> 6;
    int m = lane & 31, h = lane >> 5;
    float rn = 1.0f / sqrtf(normAcc[g]);

    {   // init Sn (bf16) and B1 = 1.5I - 0.5*Sn
        int r = t >> 2, c0 = (t & 3) * 32;
        const float* sp = Sred + (size_t)g * 16384 + r * 128 + c0;
#pragma unroll
        for (int q = 0; q < 4; q++) {
            int c = c0 + q * 8;
            float4 x0 = *(const float4*)(sp + q * 8);
            float4 x1 = *(const float4*)(sp + q * 8 + 4);
            float vv[8] = {x0.x, x0.y, x0.z, x0.w, x1.x, x1.y, x1.z, x1.w};
            Frag fs, fb;
#pragma unroll
            for (int i = 0; i < 8; i++) {
                float sv = vv[i] * rn;
                fs.s[i] = f2bf(sv);
                float bv = -0.5f * sv + ((r == c + i) ? 1.5f : 0.f);
                fb.s[i] = f2bf(bv);
            }
            *(uint4*)(Sb + swz(r, c)) = fs.q;
            *(uint4*)(Bb + swz(r, c)) = fb.q;
        }
    }
    __syncthreads();

    for (int iter = 0; iter < 4; iter++) {
        // phase1: 32 tile-tasks (16 U + 16 V) over 8 waves
#pragma unroll
        for (int i = 0; i < 4; i++) {
            int task = wave * 4 + i;
            int tmb = ((task >> 2) & 3) * 32, tnb = (task & 3) * 32;
            const unsigned short* Bsrc = (task < 16) ? Bb : Sb;
            unsigned short* dst = (task < 16) ? Ub : Vt;
            f32x16 acc;
#pragma unroll
            for (int z = 0; z < 16; z++) acc[z] = 0.f;
#pragma unroll
            for (int kk = 0; kk < 8; kk++) {
                Frag a, bfr;
                a.q = *(const uint4*)(Bb + swz(tmb + m, kk * 16 + h * 8));
                bfr.q = *(const uint4*)(Bsrc + swz(tnb + m, kk * 16 + h * 8));
                acc = __builtin_amdgcn_mfma_f32_32x32x16_bf16(a.v, bfr.v, acc, 0, 0, 0);
            }
            // transposed packed store (4 consecutive rows share a granule)
#pragma unroll
            for (int q = 0; q < 4; q++) {
                union { unsigned short s[4]; uint2 u; } pk;
#pragma unroll
                for (int j = 0; j < 4; j++) pk.s[j] = f2bf(acc[q * 4 + j]);
                int rr = tmb + q * 8 + h * 4;
                int cc = tnb + m;
                *(uint2*)(dst + swz(cc, rr)) = pk.u;
            }
        }
        __syncthreads();
        // phase2: 16 tile-tasks, B = 1.5B - 0.5*U*V (in place, lane-owned elems)
#pragma unroll
        for (int i = 0; i < 2; i++) {
            int task = wave * 2 + i;
            int tmb = (task >> 2) * 32, tnb = (task & 3) * 32;
            f32x16 acc;
#pragma unroll
            for (int z = 0; z < 16; z++) acc[z] = 0.f;
#pragma unroll
            for (int kk = 0; kk < 8; kk++) {
                Frag a, bfr;
                a.q = *(const uint4*)(Ub + swz(tmb + m, kk * 16 + h * 8));
                bfr.q = *(const uint4*)(Vt + swz(tnb + m, kk * 16 + h * 8));
                acc = __builtin_amdgcn_mfma_f32_32x32x16_bf16(a.v, bfr.v, acc, 0, 0, 0);
            }
#pragma unroll
            for (int reg = 0; reg < 16; reg++) {
                int rr = tmb + (reg & 3) + 8 * (reg >> 2) + 4 * h;
                int cc = tnb + m;
                int e = swz(rr, cc);
                Bb[e] = f2bf(1.5f * bf2f(Bb[e]) - 0.5f * acc[reg]);
            }
        }
        __syncthreads();
    }
    {   // write B5 row-major bf16 to global
        int r = t >> 2, c0 = (t & 3) * 32;
        unsigned short* bp = Bt + (size_t)g * 16384 + r * 128;
#pragma unroll
        for (int q = 0; q < 4; q++) {
            uint4 dd = *(const uint4*)(Bb + swz(r, c0 + q * 8));
            *(uint4*)(bp + c0 + q * 8) = dd;
        }
    }
}

// -------------------------------------------- K5: W = (B5 * Zc) * norm^{-1/2}
// v2: stage the 128x128 Zc slice in LDS (coalesced uint4 global loads), build the
// transposed B-fragment from 8x ds_read_u16 in the swizzled tile. K=128 = one tile.
__global__ __launch_bounds__(256) void k_wgemm(const unsigned short* __restrict__ Zc,
                                               const unsigned short* __restrict__ Bt,
                                               const float* __restrict__ normAcc,
                                               float* __restrict__ out) {
    __shared__ unsigned short Ab[16384];   // B5 tile, swizzled [row][k]
    __shared__ unsigned short Zt[16384];   // Zc slice, swizzled [k][col]
    int nt = blockIdx.x, g = blockIdx.y;
    int t = threadIdx.x, lane = t & 63, wave = t >> 6;
    int m = lane & 31, h = lane >> 5;

    const unsigned short* bg = Bt + (size_t)g * 16384;
    const unsigned short* zg = Zc + (size_t)g * NROW * D + nt * 128;
#pragma unroll
    for (int p = 0; p < 8; p++) {
        int flat = p * 256 + t;
        int r = flat >> 4, gc = flat & 15;
        uint4 da = *(const uint4*)(bg + r * 128 + gc * 8);
        uint4 dz = *(const uint4*)(zg + (size_t)r * D + gc * 8);
        *(uint4*)(Ab + swz(r, gc * 8)) = da;
        *(uint4*)(Zt + swz(r, gc * 8)) = dz;
    }
    __syncthreads();
    float ss = 1.0f / sqrtf(sqrtf(normAcc[g]));   // 1/sqrt(norm_S)

    int cw = wave * 32 + m;                        // this lane's output column (in tile)

    f32x16 acc[4];
#pragma unroll
    for (int i = 0; i < 4; i++)
#pragma unroll
        for (int z = 0; z < 16; z++) acc[i][z] = 0.f;

#pragma unroll
    for (int ks = 0; ks < 8; ks++) {
        int k0 = ks * 16 + h * 8;
        Frag b;
#pragma unroll
        for (int j = 0; j < 8; j++) b.s[j] = Zt[swz(k0 + j, cw)];
#pragma unroll
        for (int i = 0; i < 4; i++) {
            Frag a;
            a.q = *(const uint4*)(Ab + swz(i * 32 + m, k0));
            acc[i] = __builtin_amdgcn_mfma_f32_32x32x16_bf16(a.v, b.v, acc[i], 0, 0, 0);
        }
    }
    float* og = out + (size_t)(g * NROW) * D + nt * 128 + cw;
#pragma unroll
    for (int i = 0; i < 4; i++)
#pragma unroll
        for (int reg = 0; reg < 16; reg++) {
            int row = i * 32 + (reg & 3) + 8 * (reg >> 2) + 4 * h;
            og[(size_t)row * D] = acc[i][reg] * ss;
        }
}

// ------------------------------------------------------------------ launcher
extern "C" void kernel_launch(void* const* d_in, const int* in_sizes, int n_in,
                              void* d_out, int out_size, void* d_ws, size_t ws_size,
                              hipStream_t stream) {
    const float* W = (const float*)d_in[0];
    float* out = (float*)d_out;
    char* ws = (char*)d_ws;

    // ws layout (bytes): Zc bf16 [2048*9216]           @ 0        (37,748,736)
    //                    Spart f32 [16*18*128*128]     @ 37748736 (18,874,368)
    //                    Sred f32 [16*128*128]         @ 56623104 ( 1,048,576)
    //                    normAcc f32 [16]              @ 57671680 (64, padded)
    //                    Bt bf16 [16*128*128]          @ 57671744 (   524,288)
    unsigned short* Zc = (unsigned short*)(ws);
    float* Spart = (float*)(ws + 37748736ULL);
    float* Sred = (float*)(ws + 56623104ULL);
    float* normAcc = (float*)(ws + 57671680ULL);
    unsigned short* Bt = (unsigned short*)(ws + 57671744ULL);

    k_center<<<OC, 256, 0, stream>>>(W, Zc);
    k_sgemm<<<G * KSPLIT, 256, 0, stream>>>(Zc, Spart);
    hipMemsetAsync(normAcc, 0, 64, stream);
    k_reduce<<<256, 256, 0, stream>>>(Spart, Sred, normAcc);
    hipFuncSetAttribute((const void*)k_ns,
                        hipFuncAttributeMaxDynamicSharedMemorySize, 131072);
    k_ns<<<G, 512, 131072, stream>>>(Sred, normAcc, Bt);
    k_wgemm<<<dim3(72, G), 256, 0, stream>>>(Zc, Bt, normAcc, out);
}

// Round 3
// 190.322 us; speedup vs baseline: 1.0059x; 1.0059x over previous
//
#include <hip/hip_runtime.h>

// ONINorm: g=16 groups, n=128 rows/group, d=9216 cols, T=5 Newton-Schulz iters.
// Pipeline: center -> S=Zc*Zc^T -> normalize -> NS iterations -> W=B*Zc/sqrt(norm).

#define G 16
#define NROW 128
#define D 9216
#define OC 2048
#define KSPLIT 16
#define KCHUNK 576   // D / KSPLIT = 4*128 + 64
#define EPSV 1e-5f

typedef float f32x16 __attribute__((ext_vector_type(16)));
typedef __bf16 bf16x8 __attribute__((ext_vector_type(8)));

union Frag {
    uint4 q;
    unsigned short s[8];
    bf16x8 v;
};

static __device__ __forceinline__ unsigned short f2bf(float x) {
    union { float f; unsigned int u; } a; a.f = x;
    unsigned int u = a.u;
    unsigned int r = u + 0x7FFFu + ((u >> 16) & 1u);   // RNE, inputs are finite
    return (unsigned short)(r >> 16);
}

// Swizzled 128x128 bf16 matrix layout (element index). Granule = 8 elems = 16B.
// addr(r,c) = r*128 + ((c/8) ^ (r&15))*8 + c%8  -> frag reads are one ds_read_b128,
// rows r and r+16 share banks (2-way = free), others distinct.
static __device__ __forceinline__ int swz(int r, int c) {
    return (r << 7) + ((((c >> 3) ^ (r & 15)) << 3) | (c & 7));
}

// ---------------------------------------------------------------- K1: center
__global__ __launch_bounds__(256) void k_center(const float* __restrict__ W,
                                                unsigned short* __restrict__ Zc) {
    int row = blockIdx.x;
    int t = threadIdx.x;
    const float4* wp = (const float4*)(W + (size_t)row * D);
    float4 v[9];
    float s = 0.f;
#pragma unroll
    for (int i = 0; i < 9; i++) {
        v[i] = wp[t + i * 256];
        s += v[i].x + v[i].y + v[i].z + v[i].w;
    }
#pragma unroll
    for (int o = 32; o > 0; o >>= 1) s += __shfl_down(s, o, 64);
    __shared__ float ls[4];
    if ((t & 63) == 0) ls[t >> 6] = s;
    __syncthreads();
    float mean = (ls[0] + ls[1] + ls[2] + ls[3]) * (1.0f / 9216.0f);
    ushort4* zp = (ushort4*)(Zc + (size_t)row * D);
#pragma unroll
    for (int i = 0; i < 9; i++) {
        ushort4 o4;
        o4.x = f2bf(v[i].x - mean);
        o4.y = f2bf(v[i].y - mean);
        o4.z = f2bf(v[i].z - mean);
        o4.w = f2bf(v[i].w - mean);
        zp[t + i * 256] = o4;
    }
}

// ------------------------------------------------- K2: S partial GEMM (k-split)
// block (g, ks): S_part = Zc[:, chunk] * Zc[:, chunk]^T, chunk = 576 cols as
// 4 full 128-col steps + 1 half (64-col) step. Register-prefetch next step
// (1 wave/SIMD occupancy -> staging latency otherwise fully exposed).
__global__ __launch_bounds__(256) void k_sgemm(const unsigned short* __restrict__ Zc,
                                               float* __restrict__ Spart) {
    __shared__ unsigned short tile[NROW * 128];
    int bid = blockIdx.x;
    int g = bid / KSPLIT, ks = bid % KSPLIT;
    int t = threadIdx.x, lane = t & 63, wave = t >> 6;
    int mq = (wave & 1) * 64, nq = (wave >> 1) * 64;
    int m = lane & 31, h = lane >> 5;

    f32x16 acc[2][2];
#pragma unroll
    for (int i = 0; i < 2; i++)
#pragma unroll
        for (int j = 0; j < 2; j++)
#pragma unroll
            for (int z = 0; z < 16; z++) acc[i][j][z] = 0.f;

    const unsigned short* zg = Zc + (size_t)g * NROW * D + ks * KCHUNK;

    uint4 pf[8];
#pragma unroll
    for (int p = 0; p < 8; p++) {                      // preload step 0
        int flat = p * 256 + t, r = flat >> 4, gc = flat & 15;
        pf[p] = *(const uint4*)(zg + (size_t)r * D + gc * 8);
    }

    for (int step = 0; step < 5; step++) {
        __syncthreads();
        if (step < 4) {
#pragma unroll
            for (int p = 0; p < 8; p++) {
                int flat = p * 256 + t, r = flat >> 4, gc = flat & 15;
                *(uint4*)(tile + swz(r, gc * 8)) = pf[p];
            }
        } else {
#pragma unroll
            for (int p = 0; p < 4; p++) {
                int flat = p * 256 + t, r = flat >> 3, gc = flat & 7;
                *(uint4*)(tile + swz(r, gc * 8)) = pf[p];
            }
        }
        __syncthreads();
        if (step < 3) {                                // prefetch next full step
            int dbase = (step + 1) * 128;
#pragma unroll
            for (int p = 0; p < 8; p++) {
                int flat = p * 256 + t, r = flat >> 4, gc = flat & 15;
                pf[p] = *(const uint4*)(zg + (size_t)r * D + dbase + gc * 8);
            }
        } else if (step == 3) {                        // prefetch half step
#pragma unroll
            for (int p = 0; p < 4; p++) {
                int flat = p * 256 + t, r = flat >> 3, gc = flat & 7;
                pf[p] = *(const uint4*)(zg + (size_t)r * D + 512 + gc * 8);
            }
        }
        int kmax = (step < 4) ? 8 : 4;
#pragma unroll
        for (int kk = 0; kk < 8; kk++) {
            if (kk >= kmax) break;
            int kb = kk * 16 + h * 8;
            Frag a0, a1, b0, b1;
            a0.q = *(const uint4*)(tile + swz(mq + m, kb));
            a1.q = *(const uint4*)(tile + swz(mq + 32 + m, kb));
            b0.q = *(const uint4*)(tile + swz(nq + m, kb));
            b1.q = *(const uint4*)(tile + swz(nq + 32 + m, kb));
            acc[0][0] = __builtin_amdgcn_mfma_f32_32x32x16_bf16(a0.v, b0.v, acc[0][0], 0, 0, 0);
            acc[0][1] = __builtin_amdgcn_mfma_f32_32x32x16_bf16(a0.v, b1.v, acc[0][1], 0, 0, 0);
            acc[1][0] = __builtin_amdgcn_mfma_f32_32x32x16_bf16(a1.v, b0.v, acc[1][0], 0, 0, 0);
            acc[1][1] = __builtin_amdgcn_mfma_f32_32x32x16_bf16(a1.v, b1.v, acc[1][1], 0, 0, 0);
        }
    }
    float* sp = Spart + (size_t)(g * KSPLIT + ks) * 16384;
#pragma unroll
    for (int i = 0; i < 2; i++)
#pragma unroll
        for (int j = 0; j < 2; j++)
#pragma unroll
            for (int reg = 0; reg < 16; reg++) {
                int row = (reg & 3) + 8 * (reg >> 2) + 4 * h;
                sp[(mq + i * 32 + row) * 128 + nq + j * 32 + m] = acc[i][j][reg];
            }
}

// ------------------- K3: reduce partials + eps*I + per-block fro-norm partial
__global__ __launch_bounds__(256) void k_reduce(const float* __restrict__ Spart,
                                                float* __restrict__ Sred,
                                                float* __restrict__ normPart) {
    int b = blockIdx.x;
    int g = b >> 4, part = b & 15;
    int el = part * 1024 + threadIdx.x * 4;
    float4 s = {0.f, 0.f, 0.f, 0.f};
    for (int ks = 0; ks < KSPLIT; ks++) {
        float4 p = *(const float4*)(Spart + (size_t)(g * KSPLIT + ks) * 16384 + el);
        s.x += p.x; s.y += p.y; s.z += p.z; s.w += p.w;
    }
    int r = el >> 7, c = el & 127;
    if (r >= c && r <= c + 3) {
        if (r == c) s.x += EPSV;
        else if (r == c + 1) s.y += EPSV;
        else if (r == c + 2) s.z += EPSV;
        else s.w += EPSV;
    }
    *(float4*)(Sred + (size_t)g * 16384 + el) = s;
    float sq = s.x * s.x + s.y * s.y + s.z * s.z + s.w * s.w;
#pragma unroll
    for (int o = 32; o > 0; o >>= 1) sq += __shfl_down(sq, o, 64);
    __shared__ float ls[4];
    if ((threadIdx.x & 63) == 0) ls[threadIdx.x >> 6] = sq;
    __syncthreads();
    if (threadIdx.x == 0) normPart[b] = ls[0] + ls[1] + ls[2] + ls[3];
}

// ------------------------------------------------ K4: Newton-Schulz (one blk/group)
// B1 = 1.5I - 0.5*Sn analytically (skips iter 1), then 4 iterations.
// B is a polynomial in symmetric S => symmetric; U = B*B^T is bitwise symmetric.
//   phase1: Ub = B*B^T (stored transposed = itself), Vt = (-0.5*B*S)^T.
//   phase2: Bnew = U*(Vt^T) + (1.5*I)*B  -- the 1.5B term fused as 2 extra MFMA
//           k-steps with a synthesized 1.5*I A-fragment; result kept in regs
//           across a barrier, then transposed-stored into Bb (B^T ~= B).
__global__ __launch_bounds__(512) void k_ns(const float* __restrict__ Sred,
                                            const float* __restrict__ normPart,
                                            unsigned short* __restrict__ Bt) {
    extern __shared__ unsigned short sm[];
    unsigned short* Bb = sm;
    unsigned short* Sb = sm + 16384;
    unsigned short* Ub = sm + 32768;
    unsigned short* Vt = sm + 49152;
    int g = blockIdx.x;
    int t = threadIdx.x, lane = t & 63, wave = t >> 6;
    int m = lane & 31, h = lane >> 5;

    float ns = 0.f;
#pragma unroll
    for (int i = 0; i < 16; i++) ns += normPart[g * 16 + i];
    float rn = 1.0f / sqrtf(ns);

    {   // init Sn (bf16) and B1 = 1.5I - 0.5*Sn
        int r = t >> 2, c0 = (t & 3) * 32;
        const float* sp = Sred + (size_t)g * 16384 + r * 128 + c0;
#pragma unroll
        for (int q = 0; q < 4; q++) {
            int c = c0 + q * 8;
            float4 x0 = *(const float4*)(sp + q * 8);
            float4 x1 = *(const float4*)(sp + q * 8 + 4);
            float vv[8] = {x0.x, x0.y, x0.z, x0.w, x1.x, x1.y, x1.z, x1.w};
            Frag fs, fb;
#pragma unroll
            for (int i = 0; i < 8; i++) {
                float sv = vv[i] * rn;
                fs.s[i] = f2bf(sv);
                float bv = -0.5f * sv + ((r == c + i) ? 1.5f : 0.f);
                fb.s[i] = f2bf(bv);
            }
            *(uint4*)(Sb + swz(r, c)) = fs.q;
            *(uint4*)(Bb + swz(r, c)) = fb.q;
        }
    }

    Frag fI[2];   // 1.5*I A-fragments for the fused identity k-steps
#pragma unroll
    for (int kk2 = 0; kk2 < 2; kk2++)
#pragma unroll
        for (int j = 0; j < 8; j++)
            fI[kk2].s[j] = (m == kk2 * 16 + h * 8 + j) ? (unsigned short)0x3FC0 : (unsigned short)0;

    __syncthreads();

    for (int iter = 0; iter < 4; iter++) {
        // phase1: 32 tile-tasks (16 U + 16 V) over 8 waves
#pragma unroll
        for (int i = 0; i < 4; i++) {
            int task = wave * 4 + i;
            int tmb = ((task >> 2) & 3) * 32, tnb = (task & 3) * 32;
            const unsigned short* Bsrc = (task < 16) ? Bb : Sb;
            unsigned short* dst = (task < 16) ? Ub : Vt;
            float sc = (task < 16) ? 1.0f : -0.5f;
            f32x16 acc;
#pragma unroll
            for (int z = 0; z < 16; z++) acc[z] = 0.f;
#pragma unroll
            for (int kk = 0; kk < 8; kk++) {
                Frag a, bfr;
                a.q = *(const uint4*)(Bb + swz(tmb + m, kk * 16 + h * 8));
                bfr.q = *(const uint4*)(Bsrc + swz(tnb + m, kk * 16 + h * 8));
                acc = __builtin_amdgcn_mfma_f32_32x32x16_bf16(a.v, bfr.v, acc, 0, 0, 0);
            }
            // transposed packed store (4 consecutive rows share one 8B write)
#pragma unroll
            for (int q = 0; q < 4; q++) {
                union { unsigned short s[4]; uint2 u; } pk;
#pragma unroll
                for (int j = 0; j < 4; j++) pk.s[j] = f2bf(sc * acc[q * 4 + j]);
                *(uint2*)(dst + swz(tnb + m, tmb + q * 8 + h * 4)) = pk.u;
            }
        }
        __syncthreads();
        // phase2 compute: 16 tasks, Bnew = U*V' + 1.5I*B, kept in registers
        f32x16 acc2[2];
#pragma unroll
        for (int i = 0; i < 2; i++) {
            int task = wave * 2 + i;
            int tmb = (task >> 2) * 32, tnb = (task & 3) * 32;
#pragma unroll
            for (int z = 0; z < 16; z++) acc2[i][z] = 0.f;
#pragma unroll
            for (int kk = 0; kk < 8; kk++) {
                Frag a, bfr;
                a.q = *(const uint4*)(Ub + swz(tmb + m, kk * 16 + h * 8));
                bfr.q = *(const uint4*)(Vt + swz(tnb + m, kk * 16 + h * 8));
                acc2[i] = __builtin_amdgcn_mfma_f32_32x32x16_bf16(a.v, bfr.v, acc2[i], 0, 0, 0);
            }
#pragma unroll
            for (int kk2 = 0; kk2 < 2; kk2++) {
                Frag bfr;
                bfr.q = *(const uint4*)(Bb + swz(tnb + m, tmb + kk2 * 16 + h * 8));
                acc2[i] = __builtin_amdgcn_mfma_f32_32x32x16_bf16(fI[kk2].v, bfr.v, acc2[i], 0, 0, 0);
            }
        }
        __syncthreads();
        // phase2 store: transposed packed store of Bnew into Bb (B^T ~= B)
#pragma unroll
        for (int i = 0; i < 2; i++) {
            int task = wave * 2 + i;
            int tmb = (task >> 2) * 32, tnb = (task & 3) * 32;
#pragma unroll
            for (int q = 0; q < 4; q++) {
                union { unsigned short s[4]; uint2 u; } pk;
#pragma unroll
                for (int j = 0; j < 4; j++) pk.s[j] = f2bf(acc2[i][q * 4 + j]);
                *(uint2*)(Bb + swz(tnb + m, tmb + q * 8 + h * 4)) = pk.u;
            }
        }
        __syncthreads();
    }
    {   // write B5 row-major bf16 to global
        int r = t >> 2, c0 = (t & 3) * 32;
        unsigned short* bp = Bt + (size_t)g * 16384 + r * 128;
#pragma unroll
        for (int q = 0; q < 4; q++) {
            uint4 dd = *(const uint4*)(Bb + swz(r, c0 + q * 8));
            *(uint4*)(bp + c0 + q * 8) = dd;
        }
    }
}

// -------------------------------------------- K5: W = (B5 * Zc) * norm^{-1/2}
__global__ __launch_bounds__(256) void k_wgemm(const unsigned short* __restrict__ Zc,
                                               const unsigned short* __restrict__ Bt,
                                               const float* __restrict__ normPart,
                                               float* __restrict__ out) {
    __shared__ unsigned short Ab[16384];   // B5 tile, swizzled [row][k]
    __shared__ unsigned short Zt[16384];   // Zc slice, swizzled [k][col]
    int nt = blockIdx.x, g = blockIdx.y;
    int t = threadIdx.x, lane = t & 63, wave = t >> 6;
    int m = lane & 31, h = lane >> 5;

    const unsigned short* bg = Bt + (size_t)g * 16384;
    const unsigned short* zg = Zc + (size_t)g * NROW * D + nt * 128;
#pragma unroll
    for (int p = 0; p < 8; p++) {
        int flat = p * 256 + t;
        int r = flat >> 4, gc = flat & 15;
        uint4 da = *(const uint4*)(bg + r * 128 + gc * 8);
        uint4 dz = *(const uint4*)(zg + (size_t)r * D + gc * 8);
        *(uint4*)(Ab + swz(r, gc * 8)) = da;
        *(uint4*)(Zt + swz(r, gc * 8)) = dz;
    }
    __syncthreads();
    float nsum = 0.f;
#pragma unroll
    for (int i = 0; i < 16; i++) nsum += normPart[g * 16 + i];
    float ss = 1.0f / sqrtf(sqrtf(nsum));   // 1/sqrt(norm_S)

    int cw = wave * 32 + m;                  // this lane's output column (in tile)

    f32x16 acc[4];
#pragma unroll
    for (int i = 0; i < 4; i++)
#pragma unroll
        for (int z = 0; z < 16; z++) acc[i][z] = 0.f;

#pragma unroll
    for (int ks = 0; ks < 8; ks++) {
        int k0 = ks * 16 + h * 8;
        Frag b;
#pragma unroll
        for (int j = 0; j < 8; j++) b.s[j] = Zt[swz(k0 + j, cw)];
#pragma unroll
        for (int i = 0; i < 4; i++) {
            Frag a;
            a.q = *(const uint4*)(Ab + swz(i * 32 + m, k0));
            acc[i] = __builtin_amdgcn_mfma_f32_32x32x16_bf16(a.v, b.v, acc[i], 0, 0, 0);
        }
    }
    float* og = out + (size_t)(g * NROW) * D + nt * 128 + cw;
#pragma unroll
    for (int i = 0; i < 4; i++)
#pragma unroll
        for (int reg = 0; reg < 16; reg++) {
            int row = i * 32 + (reg & 3) + 8 * (reg >> 2) + 4 * h;
            og[(size_t)row * D] = acc[i][reg] * ss;
        }
}

// ------------------------------------------------------------------ launcher
extern "C" void kernel_launch(void* const* d_in, const int* in_sizes, int n_in,
                              void* d_out, int out_size, void* d_ws, size_t ws_size,
                              hipStream_t stream) {
    const float* W = (const float*)d_in[0];
    float* out = (float*)d_out;
    char* ws = (char*)d_ws;

    // ws layout (bytes): Zc bf16 [2048*9216]        @ 0        (37,748,736)
    //                    Spart f32 [16*16*128*128]  @ 37748736 (16,777,216)
    //                    Sred f32 [16*128*128]      @ 54525952 ( 1,048,576)
    //                    normPart f32 [256]         @ 55574528 (     1,024)
    //                    Bt bf16 [16*128*128]       @ 55575552 (   524,288)
    unsigned short* Zc = (unsigned short*)(ws);
    float* Spart = (float*)(ws + 37748736ULL);
    float* Sred = (float*)(ws + 54525952ULL);
    float* normPart = (float*)(ws + 55574528ULL);
    unsigned short* Bt = (unsigned short*)(ws + 55575552ULL);

    k_center<<<OC, 256, 0, stream>>>(W, Zc);
    k_sgemm<<<G * KSPLIT, 256, 0, stream>>>(Zc, Spart);
    k_reduce<<<256, 256, 0, stream>>>(Spart, Sred, normPart);
    hipFuncSetAttribute((const void*)k_ns,
                        hipFuncAttributeMaxDynamicSharedMemorySize, 131072);
    k_ns<<<G, 512, 131072, stream>>>(Sred, normPart, Bt);
    k_wgemm<<<dim3(72, G), 256, 0, stream>>>(Zc, Bt, normPart, out);
}

// Round 5
// 185.783 us; speedup vs baseline: 1.0305x; 1.0244x over previous
//
#include <hip/hip_runtime.h>

// ONINorm: g=16 groups, n=128 rows/group, d=9216 cols, T=5 Newton-Schulz iters.
// v5 (4 kernels, no centering pass):
//   S = Z*Z^T - d*mu*mu^T  (rank-1 correction instead of materializing Zc)
//   W = (B5*Z)*ss - (B5*mu)*ss*1^T
// K1 sgemm: read W f32, cast->bf16 (tile + global byproduct Zraw), f32 rowsums,
//           S partials. K2 reduce: partials + correction + eps + fro-norm.
// K3 ns: Newton-Schulz + c=B5*mu. K4 wgemm: out = B5*Zraw*ss - c*ss.

#define G 16
#define NROW 128
#define D 9216
#define OC 2048
#define KSPLIT 16
#define KCHUNK 576   // D / KSPLIT = 4*128 + 64
#define EPSV 1e-5f

typedef float f32x16 __attribute__((ext_vector_type(16)));
typedef __bf16 bf16x8 __attribute__((ext_vector_type(8)));

union Frag {
    uint4 q;
    unsigned short s[8];
    bf16x8 v;
};

static __device__ __forceinline__ unsigned short f2bf(float x) {
    union { float f; unsigned int u; } a; a.f = x;
    unsigned int u = a.u;
    unsigned int r = u + 0x7FFFu + ((u >> 16) & 1u);   // RNE, inputs are finite
    return (unsigned short)(r >> 16);
}

static __device__ __forceinline__ float bf2f(unsigned short s) {
    union { unsigned int u; float f; } a; a.u = ((unsigned int)s) << 16;
    return a.f;
}

// Swizzled 128x128 bf16 tile layout. Granule = 8 elems = 16B.
// addr(r,c) = r*128 + ((c/8) ^ (r&15))*8 + c%8
static __device__ __forceinline__ int swz(int r, int c) {
    return (r << 7) + ((((c >> 3) ^ (r & 15)) << 3) | (c & 7));
}

// --------------- K1: G partials from raw W + Zraw bf16 byproduct + rowsums ----
__global__ __launch_bounds__(256) void k_sgemm(const float* __restrict__ W,
                                               unsigned short* __restrict__ Zraw,
                                               float* __restrict__ Spart,
                                               float* __restrict__ rowsumPart) {
    __shared__ unsigned short tile[NROW * 128];
    __shared__ float rsum[NROW];
    int bid = blockIdx.x;
    int g = bid >> 4, ks = bid & 15;
    int t = threadIdx.x, lane = t & 63, wave = t >> 6;
    int mq = (wave & 1) * 64, nq = (wave >> 1) * 64;
    int m = lane & 31, h = lane >> 5;

    if (t < 128) rsum[t] = 0.f;

    f32x16 acc[2][2];
#pragma unroll
    for (int i = 0; i < 2; i++)
#pragma unroll
        for (int j = 0; j < 2; j++)
#pragma unroll
            for (int z = 0; z < 16; z++) acc[i][j][z] = 0.f;

    float rs[16], rsh[8];
#pragma unroll
    for (int i = 0; i < 16; i++) rs[i] = 0.f;
#pragma unroll
    for (int i = 0; i < 8; i++) rsh[i] = 0.f;

    const float* wg = W + (size_t)g * NROW * D + ks * KCHUNK;
    unsigned short* zo = Zraw + (size_t)g * NROW * D + ks * KCHUNK;

    float4 pf[16];
#pragma unroll
    for (int p = 0; p < 16; p++) {                 // preload full step 0
        int fl = p * 256 + t, r = fl >> 5, cf = fl & 31;
        pf[p] = *(const float4*)(wg + (size_t)r * D + cf * 4);
    }

    for (int step = 0; step < 5; step++) {
        __syncthreads();
        if (step < 4) {
            int dbase = step * 128;
#pragma unroll
            for (int p = 0; p < 16; p++) {
                int fl = p * 256 + t, r = fl >> 5, cf = fl & 31;
                float4 x = pf[p];
                rs[p] += x.x + x.y + x.z + x.w;
                ushort4 pk;
                pk.x = f2bf(x.x); pk.y = f2bf(x.y);
                pk.z = f2bf(x.z); pk.w = f2bf(x.w);
                *(ushort4*)(zo + (size_t)r * D + dbase + cf * 4) = pk;
                union { ushort4 s4; uint2 u; } cv; cv.s4 = pk;
                *(uint2*)(tile + swz(r, cf * 4)) = cv.u;
            }
        } else {
#pragma unroll
            for (int p = 0; p < 8; p++) {
                int fl = p * 256 + t, r = fl >> 4, cf = fl & 15;
                float4 x = pf[p];
                rsh[p] += x.x + x.y + x.z + x.w;
                ushort4 pk;
                pk.x = f2bf(x.x); pk.y = f2bf(x.y);
                pk.z = f2bf(x.z); pk.w = f2bf(x.w);
                *(ushort4*)(zo + (size_t)r * D + 512 + cf * 4) = pk;
                union { ushort4 s4; uint2 u; } cv; cv.s4 = pk;
                *(uint2*)(tile + swz(r, cf * 4)) = cv.u;
            }
        }
        __syncthreads();
        if (step < 3) {                            // prefetch next full step
            int dbase = (step + 1) * 128;
#pragma unroll
            for (int p = 0; p < 16; p++) {
                int fl = p * 256 + t, r = fl >> 5, cf = fl & 31;
                pf[p] = *(const float4*)(wg + (size_t)r * D + dbase + cf * 4);
            }
        } else if (step == 3) {                    // prefetch half step
#pragma unroll
            for (int p = 0; p < 8; p++) {
                int fl = p * 256 + t, r = fl >> 4, cf = fl & 15;
                pf[p] = *(const float4*)(wg + (size_t)r * D + 512 + cf * 4);
            }
        }
        int kmax = (step < 4) ? 8 : 4;
#pragma unroll
        for (int kk = 0; kk < 8; kk++) {
            if (kk >= kmax) break;
            int kb = kk * 16 + h * 8;
            Frag a0, a1, b0, b1;
            a0.q = *(const uint4*)(tile + swz(mq + m, kb));
            a1.q = *(const uint4*)(tile + swz(mq + 32 + m, kb));
            b0.q = *(const uint4*)(tile + swz(nq + m, kb));
            b1.q = *(const uint4*)(tile + swz(nq + 32 + m, kb));
            acc[0][0] = __builtin_amdgcn_mfma_f32_32x32x16_bf16(a0.v, b0.v, acc[0][0], 0, 0, 0);
            acc[0][1] = __builtin_amdgcn_mfma_f32_32x32x16_bf16(a0.v, b1.v, acc[0][1], 0, 0, 0);
            acc[1][0] = __builtin_amdgcn_mfma_f32_32x32x16_bf16(a1.v, b0.v, acc[1][0], 0, 0, 0);
            acc[1][1] = __builtin_amdgcn_mfma_f32_32x32x16_bf16(a1.v, b1.v, acc[1][1], 0, 0, 0);
        }
    }
    float* sp = Spart + (size_t)bid * 16384;
#pragma unroll
    for (int i = 0; i < 2; i++)
#pragma unroll
        for (int j = 0; j < 2; j++)
#pragma unroll
            for (int reg = 0; reg < 16; reg++) {
                int row = (reg & 3) + 8 * (reg >> 2) + 4 * h;
                sp[(mq + i * 32 + row) * 128 + nq + j * 32 + m] = acc[i][j][reg];
            }
    // fold per-thread rowsums into LDS, then one global write
#pragma unroll
    for (int p = 0; p < 16; p++) atomicAdd(&rsum[p * 8 + (t >> 5)], rs[p]);
#pragma unroll
    for (int p = 0; p < 8; p++) atomicAdd(&rsum[p * 16 + (t >> 4)], rsh[p]);
    __syncthreads();
    if (t < 128) rowsumPart[bid * 128 + t] = rsum[t];
}

// ------- K2: reduce partials - d*mu*mu^T + eps*I + per-block fro-norm partial --
__global__ __launch_bounds__(256) void k_reduce(const float* __restrict__ Spart,
                                                const float* __restrict__ rowsumPart,
                                                float* __restrict__ Sred,
                                                float* __restrict__ normPart) {
    __shared__ float muv[128];
    __shared__ float ls[4];
    int b = blockIdx.x;
    int g = b >> 4, part = b & 15;
    int t = threadIdx.x;
    if (t < 128) {
        float s = 0.f;
        for (int ks = 0; ks < KSPLIT; ks++) s += rowsumPart[(g * 16 + ks) * 128 + t];
        muv[t] = s * (1.0f / 9216.0f);
    }
    __syncthreads();
    int el = part * 1024 + t * 4;
    float4 s = {0.f, 0.f, 0.f, 0.f};
    for (int ks = 0; ks < KSPLIT; ks++) {
        float4 p = *(const float4*)(Spart + (size_t)(g * KSPLIT + ks) * 16384 + el);
        s.x += p.x; s.y += p.y; s.z += p.z; s.w += p.w;
    }
    int r = el >> 7, c = el & 127;
    float4 mc = *(float4*)&muv[c];
    float dm = 9216.0f * muv[r];
    s.x -= dm * mc.x; s.y -= dm * mc.y; s.z -= dm * mc.z; s.w -= dm * mc.w;
    if (r >= c && r <= c + 3) {
        if (r == c) s.x += EPSV;
        else if (r == c + 1) s.y += EPSV;
        else if (r == c + 2) s.z += EPSV;
        else s.w += EPSV;
    }
    *(float4*)(Sred + (size_t)g * 16384 + el) = s;
    float sq = s.x * s.x + s.y * s.y + s.z * s.z + s.w * s.w;
#pragma unroll
    for (int o = 32; o > 0; o >>= 1) sq += __shfl_down(sq, o, 64);
    if ((t & 63) == 0) ls[t >> 6] = sq;
    __syncthreads();
    if (t == 0) normPart[b] = ls[0] + ls[1] + ls[2] + ls[3];
}

// ------------------------------- K3: Newton-Schulz (one blk/group) + c = B5*mu --
__global__ __launch_bounds__(512) void k_ns(const float* __restrict__ Sred,
                                            const float* __restrict__ normPart,
                                            const float* __restrict__ rowsumPart,
                                            unsigned short* __restrict__ Bt,
                                            float* __restrict__ cvec) {
    extern __shared__ unsigned short sm[];
    unsigned short* Bb = sm;
    unsigned short* Sb = sm + 16384;
    unsigned short* Ub = sm + 32768;
    unsigned short* Vt = sm + 49152;
    int g = blockIdx.x;
    int t = threadIdx.x, lane = t & 63, wave = t >> 6;
    int m = lane & 31, h = lane >> 5;

    float ns = 0.f;
#pragma unroll
    for (int i = 0; i < 16; i++) ns += normPart[g * 16 + i];
    float rn = 1.0f / sqrtf(ns);

    {   // init Sn (bf16) and B1 = 1.5I - 0.5*Sn  (each thread 1/4 row)
        int r = t >> 2, c0 = (t & 3) * 32;
        const float* sp = Sred + (size_t)g * 16384 + r * 128 + c0;
#pragma unroll
        for (int q = 0; q < 4; q++) {
            int c = c0 + q * 8;
            float4 x0 = *(const float4*)(sp + q * 8);
            float4 x1 = *(const float4*)(sp + q * 8 + 4);
            float vv[8] = {x0.x, x0.y, x0.z, x0.w, x1.x, x1.y, x1.z, x1.w};
            Frag fs, fb;
#pragma unroll
            for (int i = 0; i < 8; i++) {
                float sv = vv[i] * rn;
                fs.s[i] = f2bf(sv);
                float bv = -0.5f * sv + ((r == c + i) ? 1.5f : 0.f);
                fb.s[i] = f2bf(bv);
            }
            *(uint4*)(Sb + swz(r, c)) = fs.q;
            *(uint4*)(Bb + swz(r, c)) = fb.q;
        }
    }
    Frag fI[2];   // 1.5*I A-fragments
#pragma unroll
    for (int kk2 = 0; kk2 < 2; kk2++)
#pragma unroll
        for (int j = 0; j < 8; j++)
            fI[kk2].s[j] = (m == kk2 * 16 + h * 8 + j) ? (unsigned short)0x3FC0
                                                       : (unsigned short)0;
    __syncthreads();

    for (int iter = 0; iter < 4; iter++) {
        // phase1: 32 tile-tasks (16 U=B*B^T + 16 V=(-0.5 B*S)^T) over 8 waves
#pragma unroll
        for (int i = 0; i < 4; i++) {
            int task = wave * 4 + i;
            int tmb = ((task >> 2) & 3) * 32, tnb = (task & 3) * 32;
            const unsigned short* Bsrc = (task < 16) ? Bb : Sb;
            unsigned short* dst = (task < 16) ? Ub : Vt;
            float sc = (task < 16) ? 1.0f : -0.5f;
            f32x16 acc;
#pragma unroll
            for (int z = 0; z < 16; z++) acc[z] = 0.f;
#pragma unroll
            for (int kk = 0; kk < 8; kk++) {
                Frag a, bfr;
                a.q = *(const uint4*)(Bb + swz(tmb + m, kk * 16 + h * 8));
                bfr.q = *(const uint4*)(Bsrc + swz(tnb + m, kk * 16 + h * 8));
                acc = __builtin_amdgcn_mfma_f32_32x32x16_bf16(a.v, bfr.v, acc, 0, 0, 0);
            }
#pragma unroll
            for (int q = 0; q < 4; q++) {
                union { unsigned short s[4]; uint2 u; } pk;
#pragma unroll
                for (int j = 0; j < 4; j++) pk.s[j] = f2bf(sc * acc[q * 4 + j]);
                *(uint2*)(dst + swz(tnb + m, tmb + q * 8 + h * 4)) = pk.u;
            }
        }
        __syncthreads();
        // phase2: Bnew = U*V' + 1.5I*B in registers
        f32x16 acc2[2];
#pragma unroll
        for (int i = 0; i < 2; i++) {
            int task = wave * 2 + i;
            int tmb = (task >> 2) * 32, tnb = (task & 3) * 32;
#pragma unroll
            for (int z = 0; z < 16; z++) acc2[i][z] = 0.f;
#pragma unroll
            for (int kk = 0; kk < 8; kk++) {
                Frag a, bfr;
                a.q = *(const uint4*)(Ub + swz(tmb + m, kk * 16 + h * 8));
                bfr.q = *(const uint4*)(Vt + swz(tnb + m, kk * 16 + h * 8));
                acc2[i] = __builtin_amdgcn_mfma_f32_32x32x16_bf16(a.v, bfr.v, acc2[i], 0, 0, 0);
            }
#pragma unroll
            for (int kk2 = 0; kk2 < 2; kk2++) {
                Frag bfr;
                bfr.q = *(const uint4*)(Bb + swz(tnb + m, tmb + kk2 * 16 + h * 8));
                acc2[i] = __builtin_amdgcn_mfma_f32_32x32x16_bf16(fI[kk2].v, bfr.v, acc2[i], 0, 0, 0);
            }
        }
        __syncthreads();
#pragma unroll
        for (int i = 0; i < 2; i++) {
            int task = wave * 2 + i;
            int tmb = (task >> 2) * 32, tnb = (task & 3) * 32;
#pragma unroll
            for (int q = 0; q < 4; q++) {
                union { unsigned short s[4]; uint2 u; } pk;
#pragma unroll
                for (int j = 0; j < 4; j++) pk.s[j] = f2bf(acc2[i][q * 4 + j]);
                *(uint2*)(Bb + swz(tnb + m, tmb + q * 8 + h * 4)) = pk.u;
            }
        }
        __syncthreads();
    }
    {   // write B5 row-major bf16 to global
        int r = t >> 2, c0 = (t & 3) * 32;
        unsigned short* bp = Bt + (size_t)g * 16384 + r * 128;
#pragma unroll
        for (int q = 0; q < 4; q++) {
            uint4 dd = *(const uint4*)(Bb + swz(r, c0 + q * 8));
            *(uint4*)(bp + c0 + q * 8) = dd;
        }
    }
    // c = B5 * mu  (mu from rowsum partials; muv overlays the now-free Ub region)
    float* muv = (float*)(sm + 32768);
    if (t < 128) {
        float s = 0.f;
        for (int ks = 0; ks < KSPLIT; ks++) s += rowsumPart[(g * 16 + ks) * 128 + t];
        muv[t] = s * (1.0f / 9216.0f);
    }
    __syncthreads();
    if (t < 128) {
        float cacc = 0.f;
        for (int k = 0; k < 128; k++) cacc += bf2f(Bb[swz(t, k)]) * muv[k];
        cvec[g * 128 + t] = cacc;
    }
}

// --------------- K4: out = (B5 * Zraw)*ss - (B5*mu)*ss, row-broadcast ---------
__global__ __launch_bounds__(256) void k_wgemm(const unsigned short* __restrict__ Zraw,
                                               const unsigned short* __restrict__ Bt,
                                               const float* __restrict__ normPart,
                                               const float* __restrict__ cvec,
                                               float* __restrict__ out) {
    __shared__ unsigned short Ab[16384];   // B5 tile, swizzled [row][k]
    __shared__ unsigned short Zt[16384];   // Zraw slice, swizzled [k][col]
    __shared__ float cs[128];
    int nt = blockIdx.x, g = blockIdx.y;
    int t = threadIdx.x, lane = t & 63, wave = t >> 6;
    int m = lane & 31, h = lane >> 5;

    float nsum = 0.f;
#pragma unroll
    for (int i = 0; i < 16; i++) nsum += normPart[g * 16 + i];
    float ss = 1.0f / sqrtf(sqrtf(nsum));   // 1/sqrt(norm_S)

    const unsigned short* bg = Bt + (size_t)g * 16384;
    const unsigned short* zg = Zraw + (size_t)g * NROW * D + nt * 128;
#pragma unroll
    for (int p = 0; p < 8; p++) {
        int flat = p * 256 + t;
        int r = flat >> 4, gc = flat & 15;
        uint4 da = *(const uint4*)(bg + r * 128 + gc * 8);
        uint4 dz = *(const uint4*)(zg + (size_t)r * D + gc * 8);
        *(uint4*)(Ab + swz(r, gc * 8)) = da;
        *(uint4*)(Zt + swz(r, gc * 8)) = dz;
    }
    if (t < 128) cs[t] = cvec[g * 128 + t] * ss;
    __syncthreads();

    int cw = wave * 32 + m;                  // this lane's output column (in tile)

    f32x16 acc[4];
#pragma unroll
    for (int i = 0; i < 4; i++)
#pragma unroll
        for (int z = 0; z < 16; z++) acc[i][z] = 0.f;

#pragma unroll
    for (int ks = 0; ks < 8; ks++) {
        int k0 = ks * 16 + h * 8;
        Frag b;
#pragma unroll
        for (int j = 0; j < 8; j++) b.s[j] = Zt[swz(k0 + j, cw)];
#pragma unroll
        for (int i = 0; i < 4; i++) {
            Frag a;
            a.q = *(const uint4*)(Ab + swz(i * 32 + m, k0));
            acc[i] = __builtin_amdgcn_mfma_f32_32x32x16_bf16(a.v, b.v, acc[i], 0, 0, 0);
        }
    }
    float* og = out + (size_t)(g * NROW) * D + nt * 128 + cw;
#pragma unroll
    for (int i = 0; i < 4; i++)
#pragma unroll
        for (int reg = 0; reg < 16; reg++) {
            int row = i * 32 + (reg & 3) + 8 * (reg >> 2) + 4 * h;
            og[(size_t)row * D] = acc[i][reg] * ss - cs[row];
        }
}

// ------------------------------------------------------------------ launcher
extern "C" void kernel_launch(void* const* d_in, const int* in_sizes, int n_in,
                              void* d_out, int out_size, void* d_ws, size_t ws_size,
                              hipStream_t stream) {
    const float* W = (const float*)d_in[0];
    float* out = (float*)d_out;
    char* ws = (char*)d_ws;

    // ws layout (bytes): Zraw bf16 [2048*9216]       @ 0        (37,748,736)
    //                    Spart f32 [256*16384]       @ 37748736 (16,777,216)
    //                    Sred f32 [16*16384]         @ 54525952 ( 1,048,576)
    //                    normPart f32 [256]          @ 55574528 (     1,024)
    //                    Bt bf16 [16*16384]          @ 55575552 (   524,288)
    //                    rowsumPart f32 [16*16*128]  @ 56099840 (   131,072)
    //                    cvec f32 [16*128]           @ 56230912 (     8,192)
    unsigned short* Zraw = (unsigned short*)(ws);
    float* Spart = (float*)(ws + 37748736ULL);
    float* Sred = (float*)(ws + 54525952ULL);
    float* normPart = (float*)(ws + 55574528ULL);
    unsigned short* Bt = (unsigned short*)(ws + 55575552ULL);
    float* rowsumPart = (float*)(ws + 56099840ULL);
    float* cvec = (float*)(ws + 56230912ULL);

    k_sgemm<<<G * KSPLIT, 256, 0, stream>>>(W, Zraw, Spart, rowsumPart);
    k_reduce<<<256, 256, 0, stream>>>(Spart, rowsumPart, Sred, normPart);
    hipFuncSetAttribute((const void*)k_ns,
                        hipFuncAttributeMaxDynamicSharedMemorySize, 131072);
    k_ns<<<G, 512, 131072, stream>>>(Sred, normPart, rowsumPart, Bt, cvec);
    k_wgemm<<<dim3(72, G), 256, 0, stream>>>(Zraw, Bt, normPart, cvec, out);
}